// Round 3
// baseline (35.855 us; speedup 1.0000x reference)
//
#include <hip/hip_runtime.h>

#define BB 4096
#define NN 64
#define DD 128
#define G  4

// Fused, pipelined: per block G=4 rows of b, 256 threads.
// Phase 1 (per row, double-buffered neighbor tile in registers):
//   v[b] = sum_n softmax_n(nbr_n . Ww_b) * nbr_n   (uniform 1/N if sum(conc)==0)
//   u = [65*stu ; 64*conc + v] staged in LDS. 2 barriers per row.
// Phase 2: y = mask_s/2 * (u @ Ws + 65*bs), Ws streamed from L2.
__global__ __launch_bounds__(256, 4) void kFused(
    const float* __restrict__ stu,
    const float* __restrict__ conc,
    const float* __restrict__ nbr,
    const float* __restrict__ Ws,
    const float* __restrict__ bs,
    const float* __restrict__ Ww,
    float* __restrict__ y)
{
    const int t    = threadIdx.x;
    const int lane = t & 63;        // lane within wave
    const int cg   = t & 31;        // float4 column group (cols cg*4..+3)
    const int g8   = t >> 5;        // row group 0..7 (rows g8+8i)
    const int wv   = t >> 6;        // wave 0..3
    const int b0   = blockIdx.x * G;

    __shared__ float logits[NN];
    __shared__ __align__(16) float u[G][2 * DD];      // 4 KB
    __shared__ __align__(16) float part[4 * DD];      // 2 KB
    __shared__ __align__(16) float scratch[8 * G * DD]; // 16 KB (phase 2)

    const float4 wb = reinterpret_cast<const float4*>(Ww + DD)[cg];  // Ww_b slice

    float msk0 = 0.f, msk1 = 0.f, msk2 = 0.f, msk3 = 0.f;

    const float4* nb4 = reinterpret_cast<const float4*>(nbr);
    float4 val[8], valn[8];
#pragma unroll
    for (int i = 0; i < 8; ++i) val[i] = nb4[(size_t)b0 * 2048 + t + 256 * i];

#pragma unroll
    for (int g = 0; g < G; ++g) {
        const int b = b0 + g;

        // ---- prefetch next tile (hides HBM latency under this g's compute) ----
        if (g < G - 1) {
#pragma unroll
            for (int i = 0; i < 8; ++i)
                valn[i] = nb4[(size_t)(b + 1) * 2048 + t + 256 * i];
        }

        // ---- per-wave redundant row sums (masks), L1-hot loads ----
        float cv0 = conc[(size_t)b * DD + lane];
        float cv1 = conc[(size_t)b * DD + 64 + lane];
        float sv0 = stu [(size_t)b * DD + lane];
        float sv1 = stu [(size_t)b * DD + 64 + lane];
        float cs = cv0 + cv1, ss = sv0 + sv1;
#pragma unroll
        for (int o = 1; o < 64; o <<= 1) {
            cs += __shfl_xor(cs, o);
            ss += __shfl_xor(ss, o);
        }
        const float mg = (ss != 0.0f) ? 0.5f : 0.0f;
        if      (g == 0) msk0 = mg;
        else if (g == 1) msk1 = mg;
        else if (g == 2) msk2 = mg;
        else             msk3 = mg;

        // ---- u staging (wave 0 holds the full rows in cv/sv) ----
        if (t < 64) {
            u[g][t]           = 65.0f * sv0;
            u[g][t + 64]      = 65.0f * sv1;
            u[g][DD + t]      = 64.0f * cv0;
            u[g][DD + 64 + t] = 64.0f * cv1;
        }

        // ---- logits: per-row dot with Ww_b, half-wave reduce ----
#pragma unroll
        for (int i = 0; i < 8; ++i) {
            float x = val[i].x * wb.x + val[i].y * wb.y
                    + val[i].z * wb.z + val[i].w * wb.w;
            x += __shfl_xor(x, 1);
            x += __shfl_xor(x, 2);
            x += __shfl_xor(x, 4);
            x += __shfl_xor(x, 8);
            x += __shfl_xor(x, 16);
            if (cg == 0) logits[g8 + 8 * i] = x;
        }
        __syncthreads();                               // barrier 1: logits

        // ---- softmax, redundantly in EVERY wave (no wave0 serialization) ----
        float l = logits[lane];
        float m = l;
        m = fmaxf(m, __shfl_xor(m, 1));
        m = fmaxf(m, __shfl_xor(m, 2));
        m = fmaxf(m, __shfl_xor(m, 4));
        m = fmaxf(m, __shfl_xor(m, 8));
        m = fmaxf(m, __shfl_xor(m, 16));
        m = fmaxf(m, __shfl_xor(m, 32));
        float e = __expf(l - m);
        float sden = e;
        sden += __shfl_xor(sden, 1);
        sden += __shfl_xor(sden, 2);
        sden += __shfl_xor(sden, 4);
        sden += __shfl_xor(sden, 8);
        sden += __shfl_xor(sden, 16);
        sden += __shfl_xor(sden, 32);
        const float wlane = (cs != 0.0f) ? (e / sden) : (1.0f / 64.0f);

        // ---- weighted sum in registers; gather weights via shfl ----
        float4 a = {0.f, 0.f, 0.f, 0.f};
#pragma unroll
        for (int i = 0; i < 8; ++i) {
            float w = __shfl(wlane, g8 + 8 * i);       // lane (g8+8i) holds row weight
            a.x += w * val[i].x; a.y += w * val[i].y;
            a.z += w * val[i].z; a.w += w * val[i].w;
        }
        // fold the two row-groups within this wave (lane l <-> l^32, same cg)
        a.x += __shfl_xor(a.x, 32);
        a.y += __shfl_xor(a.y, 32);
        a.z += __shfl_xor(a.z, 32);
        a.w += __shfl_xor(a.w, 32);
        if (lane < 32)
            reinterpret_cast<float4*>(part)[wv * 32 + cg] = a;
        __syncthreads();                               // barrier 2: partials

        if (t < DD) {
            float vsum = part[t] + part[DD + t] + part[2 * DD + t] + part[3 * DD + t];
            u[g][DD + t] += vsum;                      // staged pre-barrier, visible
        }

        if (g < G - 1) {
#pragma unroll
            for (int i = 0; i < 8; ++i) val[i] = valn[i];
        }
    }
    __syncthreads();                                   // u complete

    // ---- phase 2: y[b0+r][:] = msk[r] * (u[r] @ Ws + 65*bs) ----
    float4 acc0 = {0,0,0,0}, acc1 = {0,0,0,0}, acc2 = {0,0,0,0}, acc3 = {0,0,0,0};
    const float4* Ws4 = reinterpret_cast<const float4*>(Ws);   // 256 x 32 float4
#pragma unroll 4
    for (int j = 0; j < 32; ++j) {
        const int k = g8 * 32 + j;
        float4 wvv = Ws4[k * 32 + cg];                 // coalesced, L2-resident
        float u0 = u[0][k], u1 = u[1][k], u2 = u[2][k], u3 = u[3][k];
        acc0.x += u0 * wvv.x; acc0.y += u0 * wvv.y; acc0.z += u0 * wvv.z; acc0.w += u0 * wvv.w;
        acc1.x += u1 * wvv.x; acc1.y += u1 * wvv.y; acc1.z += u1 * wvv.z; acc1.w += u1 * wvv.w;
        acc2.x += u2 * wvv.x; acc2.y += u2 * wvv.y; acc2.z += u2 * wvv.z; acc2.w += u2 * wvv.w;
        acc3.x += u3 * wvv.x; acc3.y += u3 * wvv.y; acc3.z += u3 * wvv.z; acc3.w += u3 * wvv.w;
    }
    {
        float4* pr = reinterpret_cast<float4*>(scratch);       // pr[kg][r][32]
        pr[(g8 * G + 0) * 32 + cg] = acc0;
        pr[(g8 * G + 1) * 32 + cg] = acc1;
        pr[(g8 * G + 2) * 32 + cg] = acc2;
        pr[(g8 * G + 3) * 32 + cg] = acc3;
    }
    __syncthreads();

    const int r1 = t >> 7;            // 0/1
    const int c  = t & 127;
    const float mA = r1 ? msk1 : msk0;
    const float mB = r1 ? msk3 : msk2;
    float sA = 0.0f, sB = 0.0f;
#pragma unroll
    for (int k2 = 0; k2 < 8; ++k2) {
        sA += scratch[(k2 * G + r1) * DD + c];
        sB += scratch[(k2 * G + 2 + r1) * DD + c];
    }
    const float bc = bs[c];
    y[(size_t)(b0 + r1) * DD + c]     = (sA + 65.0f * bc) * mA;
    y[(size_t)(b0 + 2 + r1) * DD + c] = (sB + 65.0f * bc) * mB;
}

extern "C" void kernel_launch(void* const* d_in, const int* in_sizes, int n_in,
                              void* d_out, int out_size, void* d_ws, size_t ws_size,
                              hipStream_t stream) {
    const float* stu  = (const float*)d_in[0];
    const float* conc = (const float*)d_in[1];
    const float* nbr  = (const float*)d_in[2];
    const float* Ws   = (const float*)d_in[3];
    const float* bs   = (const float*)d_in[4];
    const float* Ww   = (const float*)d_in[5];
    float* y = (float*)d_out;

    kFused<<<BB / G, 256, 0, stream>>>(stu, conc, nbr, Ws, bs, Ww, y);
}